// Round 6
// baseline (635.801 us; speedup 1.0000x reference)
//
#include <hip/hip_runtime.h>
#include <hip/hip_bf16.h>
#include <stdint.h>

// ---------- problem constants ----------
#define NTOK 8192   // B*T

typedef unsigned short u16;
typedef __attribute__((ext_vector_type(4))) float f32x4;
typedef __attribute__((ext_vector_type(8))) short s16x8;
typedef __attribute__((ext_vector_type(8))) u16   u16x8;
typedef __attribute__((ext_vector_type(4))) u16   u16x4;

__device__ __forceinline__ float fast_exp2(float x) {
    return __builtin_amdgcn_exp2f(x);
}
__device__ __forceinline__ u16 f2bf(float f) {
    uint32_t u = __float_as_uint(f);
    u = (u + 0x7FFFu + ((u >> 16) & 1u)) >> 16;   // RNE
    return (u16)u;
}
__device__ __forceinline__ u16 f2bf_fast(float f) {
    return (u16)((__float_as_uint(f) + 0x8000u) >> 16);
}
__device__ __forceinline__ float bf2f(u16 h) {
    return __uint_as_float(((uint32_t)h) << 16);
}
__device__ __forceinline__ void async_cp16(const void* g, void* l) {
    __builtin_amdgcn_global_load_lds(
        (const __attribute__((address_space(1))) void*)g,
        (__attribute__((address_space(3))) void*)l, 16, 0, 0);
}
__device__ __forceinline__ void wait_vm4()   { asm volatile("s_waitcnt vmcnt(4)" ::: "memory"); }
__device__ __forceinline__ void wait_vm0()   { asm volatile("s_waitcnt vmcnt(0)" ::: "memory"); }
__device__ __forceinline__ void wait_lgkm0() { asm volatile("s_waitcnt lgkmcnt(0)" ::: "memory"); }
__device__ __forceinline__ void raw_barrier(){ asm volatile("s_barrier" ::: "memory"); }

// ---------- all weight transposes in one launch: f32 [K][N] -> bf16 [N][K] ----------
struct TDesc { const float* s; u16* d; int K; int N; int tile0; };
struct TPack { TDesc t[8]; };

__global__ __launch_bounds__(256) void k_transpose_all(TPack p)
{
    __shared__ float tile[32][33];
    int bid = blockIdx.x;
    int i = 0;
    #pragma unroll
    for (int j = 1; j < 8; j++) if (bid >= p.t[j].tile0) i = j;
    const float* src = p.t[i].s;
    u16* dst = p.t[i].d;
    int K = p.t[i].K, N = p.t[i].N;
    int local = bid - p.t[i].tile0;
    int nx = N >> 5;
    int n0 = (local % nx) * 32, k0 = (local / nx) * 32;
    int tx = threadIdx.x, ty = threadIdx.y;      // block (32,8)
    #pragma unroll
    for (int r = 0; r < 32; r += 8)
        tile[ty + r][tx] = src[(size_t)(k0 + ty + r) * N + n0 + tx];
    __syncthreads();
    #pragma unroll
    for (int r = 0; r < 32; r += 8)
        dst[(size_t)(n0 + ty + r) * K + k0 + tx] = f2bf(tile[tx][ty + r]);
}

// ---------- f32 -> bf16 flat convert (also used for weight cast) ----------
__global__ __launch_bounds__(256) void k_cvt(
    const float* __restrict__ in, u16* __restrict__ out)
{
    int i = (blockIdx.x * 256 + threadIdx.x) * 4;
    f32x4 v = *(const f32x4*)&in[i];
    u16x4 o;
    #pragma unroll
    for (int j = 0; j < 4; j++) o[j] = f2bf(v[j]);
    *(u16x4*)&out[i] = o;
}

// ---------- RMSNorm: f32 in, bf16 out ----------
template<int W>
__global__ __launch_bounds__(256) void k_rmsnorm(
    const float* __restrict__ x, const float* __restrict__ w, u16* __restrict__ out)
{
    constexpr int E = W / 256;
    int row = blockIdx.x, tid = threadIdx.x;
    const float* xr = x + (size_t)row * W;
    float v[E]; float ss = 0.f;
    #pragma unroll
    for (int i = 0; i < E; i++) { v[i] = xr[tid + i * 256]; ss += v[i] * v[i]; }
    #pragma unroll
    for (int m = 1; m < 64; m <<= 1) ss += __shfl_xor(ss, m, 64);
    __shared__ float red[4];
    if ((tid & 63) == 0) red[tid >> 6] = ss;
    __syncthreads();
    ss = red[0] + red[1] + red[2] + red[3];
    float scale = rsqrtf(ss / (float)W + 1e-6f);
    u16* orow = out + (size_t)row * W;
    #pragma unroll
    for (int i = 0; i < E; i++)
        orow[tid + i * 256] = f2bf(w[tid + i * 256] * (v[i] * scale));
}

// ---------- GEMM v3: double-buffered pipelined K-loop, split-K capable ----------
// A (MxK bf16, row-major, lda) x Bt (NxK bf16, row stride ldb); K here = per-part K,
// part selected by blockIdx.z (koff = z*K).
// EPI: 1 = bf16 store; 2 = gelu(tanh)+bf16; 3 = f32 + resid; 4 = f32 atomicAdd
template<int EPI>
__global__ __launch_bounds__(256) void k_gemm(
    const u16* __restrict__ A, int lda,
    const u16* __restrict__ Bt, int ldb,
    int M, int N, int K,
    float* __restrict__ outF, u16* __restrict__ outB,
    const float* __restrict__ resid)
{
    __shared__ __align__(16) u16 As[2][4096];
    __shared__ __align__(16) u16 Bs[2][4096];
    int tid = threadIdx.x;
    int w = tid >> 6, lane = tid & 63;
    int m0 = blockIdx.y * 128, n0 = blockIdx.x * 128;
    int wm = w & 1, wn = w >> 1;
    int lr = lane & 15, lq = lane >> 4;
    int koff = blockIdx.z * K;

    f32x4 acc[4][4];
    #pragma unroll
    for (int i = 0; i < 4; i++)
        #pragma unroll
        for (int j = 0; j < 4; j++) acc[i][j] = (f32x4)(0.f);

    int ar = tid >> 2;
    int ac = (tid & 3) * 8;
    const u16* Ag = A  + (size_t)(m0 + ar) * lda + ac + koff;
    const u16* Bg = Bt + (size_t)(n0 + ar) * ldb + ac + koff;
    int lo = w * 512;

    auto stage = [&](int kt, int s) {
        const u16* a  = Ag + kt * 32;
        const u16* bp = Bg + kt * 32;
        async_cp16(a,                     &As[s][lo]);
        async_cp16(a + (size_t)64 * lda,  &As[s][lo + 2048]);
        async_cp16(bp,                    &Bs[s][lo]);
        async_cp16(bp + (size_t)64 * ldb, &Bs[s][lo + 2048]);
    };

    int nk = K >> 5;
    stage(0, 0);
    stage(1, 1);
    for (int k = 0; k < nk; k++) {
        if (k + 1 < nk) wait_vm4(); else wait_vm0();
        raw_barrier();
        int s = k & 1;
        s16x8 af[4], bfr[4];
        #pragma unroll
        for (int ms = 0; ms < 4; ms++)
            af[ms] = *reinterpret_cast<const s16x8*>(&As[s][(wm * 64 + ms * 16 + lr) * 32 + lq * 8]);
        #pragma unroll
        for (int ns = 0; ns < 4; ns++)
            bfr[ns] = *reinterpret_cast<const s16x8*>(&Bs[s][(wn * 64 + ns * 16 + lr) * 32 + lq * 8]);
        #pragma unroll
        for (int ms = 0; ms < 4; ms++)
            #pragma unroll
            for (int ns = 0; ns < 4; ns++)
                acc[ms][ns] = __builtin_amdgcn_mfma_f32_16x16x32_bf16(af[ms], bfr[ns], acc[ms][ns], 0, 0, 0);
        wait_lgkm0();
        raw_barrier();
        if (k + 2 < nk) stage(k + 2, s);
    }

    #pragma unroll
    for (int ms = 0; ms < 4; ms++) {
        #pragma unroll
        for (int ns = 0; ns < 4; ns++) {
            int col = n0 + wn * 64 + ns * 16 + lr;
            #pragma unroll
            for (int r = 0; r < 4; r++) {
                int row = m0 + wm * 64 + ms * 16 + lq * 4 + r;
                float v = acc[ms][ns][r];
                size_t idx = (size_t)row * N + col;
                if (EPI == 1) {
                    outB[idx] = f2bf(v);
                } else if (EPI == 2) {
                    float t = 0.7978845608028654f * (v + 0.044715f * v * v * v);
                    outB[idx] = f2bf(0.5f * v * (1.f + tanhf(t)));
                } else if (EPI == 3) {
                    outF[idx] = v + resid[idx];
                } else {
                    unsafeAtomicAdd(&outF[idx], v);
                }
            }
        }
    }
}

// ---------- RoPE (x8 vectorized): q [B,T,H,64], kv [B,T,H,128] -> q_r,k_r [B,H,T,64]
// q additionally scaled by 0.125*log2(e) so attn uses exp2 directly
__global__ __launch_bounds__(256) void k_rope(
    const u16* __restrict__ q, const u16* __restrict__ kv,
    const float* __restrict__ cosb, const float* __restrict__ sinb,
    u16* __restrict__ q_r, u16* __restrict__ k_r)
{
    const float QS = 0.125f * 1.4426950408889634f;
    int idx = blockIdx.x * 256 + threadIdx.x;    // B*T*H*8 threads
    int g = idx & 7;
    int h = (idx >> 3) & 15;
    int t = (idx >> 7) & 2047;
    int b = idx >> 18;
    size_t qsrc = ((size_t)((b * 2048 + t) * 16 + h)) * 64 + g * 8;
    size_t ksrc = ((size_t)((b * 2048 + t) * 16 + h)) * 128 + g * 8;
    u16x8 qa = *(const u16x8*)&q[qsrc];
    u16x8 ka = *(const u16x8*)&kv[ksrc];
    u16x8 qo, ko;
    if (g < 4) {
        int pd = ((g ^ 2) - g) * 8;
        u16x8 qp = *(const u16x8*)&q[qsrc + pd];
        u16x8 kp = *(const u16x8*)&kv[ksrc + pd];
        float sgn = (g < 2) ? -1.f : 1.f;
        const float* cp = &cosb[t * 32 + g * 8];
        const float* sp = &sinb[t * 32 + g * 8];
        #pragma unroll
        for (int j = 0; j < 8; j++) {
            float c = cp[j], s = sp[j];
            qo[j] = f2bf((bf2f(qa[j]) * c + sgn * bf2f(qp[j]) * s) * QS);
            ko[j] = f2bf(bf2f(ka[j]) * c + sgn * bf2f(kp[j]) * s);
        }
    } else {
        #pragma unroll
        for (int j = 0; j < 8; j++) {
            qo[j] = f2bf(bf2f(qa[j]) * QS);
            ko[j] = ka[j];
        }
    }
    size_t dst = ((size_t)(b * 16 + h) * 2048 + t) * 64 + g * 8;
    *(u16x8*)&q_r[dst] = qo;
    *(u16x8*)&k_r[dst] = ko;
}

// ---------- V transpose: kv [B,T,H,128] (v half) -> v_t [B,H,64,T] ----------
__global__ __launch_bounds__(256) void k_vtrans(
    const u16* __restrict__ kv, u16* __restrict__ v_t)
{
    __shared__ u16 tile[64][72];
    int bh = blockIdx.y;
    int b = bh >> 4, h = bh & 15;
    int t0 = blockIdx.x * 64;
    int tid = threadIdx.x;
    int r = tid >> 2;
    int c4 = (tid & 3) * 16;
    const u16* src = kv + ((size_t)((b * 2048 + t0 + r) * 16 + h)) * 128 + 64;
    #pragma unroll
    for (int j = 0; j < 16; j += 8)
        *(u16x8*)&tile[r][c4 + j] = *(const u16x8*)&src[c4 + j];
    __syncthreads();
    int dd = tid >> 2;
    u16* dst = v_t + ((size_t)bh * 64 + dd) * 2048 + t0;
    #pragma unroll
    for (int j0 = 0; j0 < 16; j0 += 8) {
        u16x8 vv;
        #pragma unroll
        for (int j = 0; j < 8; j++) vv[j] = tile[c4 + j0 + j][dd];
        *(u16x8*)&dst[c4 + j0] = vv;
    }
}

// ---------- flash attention v5: double-buffered K/V staging ----------
// 128 q/block (32 q/wave), 64-t tiles, no max tracking (bounded scores),
// rotated P layout (conflict-free), vmcnt(4)-pipelined staging.
__global__ __launch_bounds__(256) void k_attn(
    const u16* __restrict__ q_r, const u16* __restrict__ k_r,
    const u16* __restrict__ v_t, u16* __restrict__ ctx)
{
    __shared__ __align__(16) u16 Ks[2][4096];   // [t64][d32] x2 halves
    __shared__ __align__(16) u16 Vs[2][4096];   // [d64][t32] x2 chunks
    __shared__ __align__(16) u16 Ps[4][2048];   // per-wave [32 q][64 t], rotated
    int tid = threadIdx.x, w = tid >> 6, lane = tid & 63;
    int bh = blockIdx.y;
    int b = bh >> 4, h = bh & 15;
    int q0 = blockIdx.x * 128 + w * 32;
    const u16* Qp = q_r + (size_t)bh * 2048 * 64;
    const u16* Kp = k_r + (size_t)bh * 2048 * 64;
    const u16* Vp = v_t + (size_t)bh * 64 * 2048;
    int lr = lane & 15, lq = lane >> 4;
    int rot = (lr * 8) & 63;

    s16x8 qf[2][2];
    #pragma unroll
    for (int qc = 0; qc < 2; qc++)
        #pragma unroll
        for (int kf = 0; kf < 2; kf++)
            qf[qc][kf] = *(const s16x8*)&Qp[(size_t)(q0 + qc * 16 + lr) * 64 + kf * 32 + lq * 8];

    const u16* gstage;
    u16 *lp0, *lp1;
    size_t grow;
    if (w < 2) {
        gstage = Kp + (size_t)(lane >> 2) * 64 + w * 32 + (lane & 3) * 8;
        lp0 = &Ks[0][w * 2048]; lp1 = &Ks[1][w * 2048];
        grow = 16 * 64;
    } else {
        gstage = Vp + (size_t)(lane >> 2) * 2048 + (w - 2) * 32 + (lane & 3) * 8;
        lp0 = &Vs[0][(w - 2) * 2048]; lp1 = &Vs[1][(w - 2) * 2048];
        grow = 16 * 2048;
    }
    auto stage = [&](int kt, int s) {
        size_t goff = (w < 2) ? (size_t)kt * 64 : (size_t)kt;
        u16* lp = s ? lp1 : lp0;
        #pragma unroll
        for (int g = 0; g < 4; g++)
            async_cp16(gstage + goff + g * grow, lp + g * 512);
    };

    float l0 = 0.f, l1 = 0.f;
    f32x4 o[2][4];
    #pragma unroll
    for (int qt = 0; qt < 2; qt++)
        #pragma unroll
        for (int ds = 0; ds < 4; ds++) o[qt][ds] = (f32x4)(0.f);

    u16* Pw = Ps[w];

    stage(0, 0);
    stage(64, 1);
    for (int k = 0; k < 32; k++) {
        if (k < 31) wait_vm4(); else wait_vm0();
        raw_barrier();
        int s = k & 1;
        const u16* Ksb = Ks[s];
        const u16* Vsb = Vs[s];

        f32x4 sc[2][4];
        #pragma unroll
        for (int ns = 0; ns < 4; ns++) {
            s16x8 a0 = *(const s16x8*)&Ksb[(ns * 16 + lr) * 32 + lq * 8];
            s16x8 a1 = *(const s16x8*)&Ksb[2048 + (ns * 16 + lr) * 32 + lq * 8];
            #pragma unroll
            for (int qc = 0; qc < 2; qc++) {
                f32x4 t = (f32x4)(0.f);
                t = __builtin_amdgcn_mfma_f32_16x16x32_bf16(a0, qf[qc][0], t, 0, 0, 0);
                t = __builtin_amdgcn_mfma_f32_16x16x32_bf16(a1, qf[qc][1], t, 0, 0, 0);
                sc[qc][ns] = t;
            }
        }

        float rs0 = 0.f, rs1 = 0.f;
        #pragma unroll
        for (int ns = 0; ns < 4; ns++) {
            u16x4 pk0, pk1;
            #pragma unroll
            for (int r = 0; r < 4; r++) {
                float p0 = fast_exp2(sc[0][ns][r]);
                float p1 = fast_exp2(sc[1][ns][r]);
                rs0 += p0; rs1 += p1;
                pk0[r] = f2bf_fast(p0);
                pk1[r] = f2bf_fast(p1);
            }
            int c0 = (ns * 16 + lq * 4 + rot) & 63;
            *(u16x4*)&Pw[lr * 64 + c0] = pk0;
            *(u16x4*)&Pw[(16 + lr) * 64 + c0] = pk1;
        }
        rs0 += __shfl_xor(rs0, 16, 64);
        rs0 += __shfl_xor(rs0, 32, 64);
        rs1 += __shfl_xor(rs1, 16, 64);
        rs1 += __shfl_xor(rs1, 32, 64);
        l0 += rs0;
        l1 += rs1;

        #pragma unroll
        for (int kf = 0; kf < 2; kf++) {
            int cr = (kf * 32 + lq * 8 + rot) & 63;
            s16x8 pf0 = *(const s16x8*)&Pw[lr * 64 + cr];
            s16x8 pf1 = *(const s16x8*)&Pw[(16 + lr) * 64 + cr];
            #pragma unroll
            for (int ds = 0; ds < 4; ds++) {
                s16x8 vf = *(const s16x8*)&Vsb[kf * 2048 + (ds * 16 + lr) * 32 + lq * 8];
                o[0][ds] = __builtin_amdgcn_mfma_f32_16x16x32_bf16(pf0, vf, o[0][ds], 0, 0, 0);
                o[1][ds] = __builtin_amdgcn_mfma_f32_16x16x32_bf16(pf1, vf, o[1][ds], 0, 0, 0);
            }
        }
        wait_lgkm0();
        raw_barrier();
        if (k + 2 < 32) stage((k + 2) * 64, s);
    }

    #pragma unroll
    for (int qt = 0; qt < 2; qt++) {
        float lv = qt ? l1 : l0;
        float li[4];
        #pragma unroll
        for (int r = 0; r < 4; r++) li[r] = 1.f / __shfl(lv, lq * 4 + r, 64);
        #pragma unroll
        for (int ds = 0; ds < 4; ds++)
            #pragma unroll
            for (int r = 0; r < 4; r++) {
                int tq = q0 + qt * 16 + lq * 4 + r;
                float v = o[qt][ds][r] * li[r];
                ctx[((size_t)(b * 2048) + tq) * 1024 + h * 64 + ds * 16 + lr] = f2bf(v);
            }
    }
}

// ---------- host ----------
extern "C" void kernel_launch(void* const* d_in, const int* in_sizes, int n_in,
                              void* d_out, int out_size, void* d_ws, size_t ws_size,
                              hipStream_t stream) {
    (void)in_sizes; (void)n_in; (void)out_size; (void)ws_size;
    const float* x     = (const float*)d_in[0];
    const float* ln1   = (const float*)d_in[1];
    const float* alnw  = (const float*)d_in[2];
    const float* qkv_a = (const float*)d_in[3];
    const float* q_b   = (const float*)d_in[4];
    const float* kv_b  = (const float*)d_in[5];
    const float* o_a   = (const float*)d_in[6];
    const float* o_b   = (const float*)d_in[7];
    const float* ln2   = (const float*)d_in[8];
    const float* in_a  = (const float*)d_in[9];
    const float* in_b  = (const float*)d_in[10];
    const float* out_a = (const float*)d_in[11];
    const float* out_b = (const float*)d_in[12];
    const float* cosb  = (const float*)d_in[13];
    const float* sinb  = (const float*)d_in[14];
    float* out = (float*)d_out;
    char* ws = (char*)d_ws;

    // ---- workspace map (peak 149,946,368 B, same as prior rounds) ----
    // weights bf16 [0, 15728640)
    u16* wqkv = (u16*)ws;              // 768x1024
    u16* wq   = wqkv + 786432;         // 1024x512
    u16* wkv  = wq   + 524288;         // 2048x256
    u16* wob  = wkv  + 524288;         // 1024x512 (o_b^T)
    u16* wia  = wob  + 524288;         // 384x1024
    u16* wib  = wia  + 393216;         // 4096x384
    u16* woa2 = wib  + 1572864;        // 384x4096 (out_a^T)
    u16* wob2 = woa2 + 1572864;        // 1024x384
    u16* woan = wob2 + 393216;         // 1024x512 (o_a cast, not transposed)
    u16* woab = woan + 524288;         // 1024x1024 fused (o_a@o_b)^T
    // f32 atomic accumulators, zeroed once per launch [15728640, 66060288)
    float* lat_raw = (float*)(ws + 15728640);   // 8192x768
    float* t1f     = (float*)(ws + 40894464);   // 8192x384
    float* t3f     = (float*)(ws + 53477376);   // 8192x384
    // general region
    char* G = ws + 66060288;
    u16*  hbuf  = (u16*)(G + 0);              // 8192x1024   [rms1 -> qkv]
    u16*  lat   = (u16*)(G + 16777216);       // 8192x768    [rms768 -> kv_b]
    u16*  qbuf  = (u16*)(G + 29360128);       // 8192x1024   [q_b -> rope]
    u16*  kvbuf = (u16*)(G + 46137344);       // 8192x2048   [kv_b -> vtrans]
    u16*  q_r   = (u16*)(G + 0);              // reuse hbuf  [rope -> attn]
    u16*  k_r   = (u16*)(ws + 15728640);      // reuse lat_raw [rope -> attn]
    u16*  v_t   = (u16*)(G + 16777216);       // reuse lat   [vtrans -> attn]
    u16*  ctx   = (u16*)(G + 33554432);       // [attn -> o-gemm]
    float* x2   = (float*)(G + 50331648);     // 8192x1024 f32 [o-gemm -> final]
    u16*  h2    = (u16*)(G + 0);              // reuse q_r   [rms2 -> in_a]
    u16*  t1    = (u16*)(G + 16777216);       // reuse v_t   [cvt1 -> in_b2]
    u16*  t2h   = (u16*)(ws + 15728640);      // 8192x2048, reuse k_r/t1f zone
    u16*  t3    = (u16*)(G + 23068672);       // [cvt3 -> out_b]

    // zero all f32 atomic accumulators in one shot
    hipMemsetAsync(ws + 15728640, 0, 50331648, stream);

    TPack tp;
    tp.t[0] = { qkv_a, wqkv, 1024, 768,  0 };
    tp.t[1] = { q_b,   wq,   512,  1024, 768 };
    tp.t[2] = { kv_b,  wkv,  256,  2048, 1280 };
    tp.t[3] = { o_b,   wob,  512,  1024, 1792 };
    tp.t[4] = { in_a,  wia,  1024, 384,  2304 };
    tp.t[5] = { in_b,  wib,  384,  4096, 2688 };
    tp.t[6] = { out_a, woa2, 4096, 384,  4224 };
    tp.t[7] = { out_b, wob2, 384,  1024, 5760 };
    k_transpose_all<<<6144, dim3(32, 8), 0, stream>>>(tp);
    k_cvt<<<512, 256, 0, stream>>>(o_a, woan);            // bf16 cast of o_a
    // fused o-weight: W^T = o_b^T @ o_a  (bf16), [1024][1024]
    k_gemm<1><<<dim3(8, 8, 1), 256, 0, stream>>>(wob, 512, woan, 512, 1024, 1024, 512, nullptr, woab, nullptr);

    k_rmsnorm<1024><<<NTOK, 256, 0, stream>>>(x, ln1, hbuf);
    k_gemm<4><<<dim3(6, 64, 2), 256, 0, stream>>>(hbuf, 1024, wqkv, 1024, NTOK, 768, 512, lat_raw, nullptr, nullptr);
    k_rmsnorm<768><<<NTOK, 256, 0, stream>>>(lat_raw, alnw, lat);
    k_gemm<1><<<dim3(8, 64, 1),  256, 0, stream>>>(lat,       768, wq,  512, NTOK, 1024, 512, nullptr, qbuf,  nullptr);
    k_gemm<1><<<dim3(16, 64, 1), 256, 0, stream>>>(lat + 512, 768, wkv, 256, NTOK, 2048, 256, nullptr, kvbuf, nullptr);
    k_rope<<<4096, 256, 0, stream>>>(qbuf, kvbuf, cosb, sinb, q_r, k_r);
    k_vtrans<<<dim3(32, 64), 256, 0, stream>>>(kvbuf, v_t);
    k_attn<<<dim3(16, 64), 256, 0, stream>>>(q_r, k_r, v_t, ctx);
    // attn_out + residual in one GEMM via fused weight
    k_gemm<3><<<dim3(8, 64, 1), 256, 0, stream>>>(ctx, 1024, woab, 1024, NTOK, 1024, 1024, x2, nullptr, x);
    k_rmsnorm<1024><<<NTOK, 256, 0, stream>>>(x2, ln2, h2);
    k_gemm<4><<<dim3(3, 64, 2), 256, 0, stream>>>(h2, 1024, wia, 1024, NTOK, 384, 512, t1f, nullptr, nullptr);
    k_cvt<<<3072, 256, 0, stream>>>(t1f, t1);
    // FFN mid in two 2048-col halves sharing one t2 buffer
    k_gemm<2><<<dim3(16, 64, 1), 256, 0, stream>>>(t1, 384, wib,              384, NTOK, 2048, 384, nullptr, t2h, nullptr);
    k_gemm<4><<<dim3(3, 64, 2),  256, 0, stream>>>(t2h, 2048, woa2,          4096, NTOK, 384, 1024, t3f, nullptr, nullptr);
    k_gemm<2><<<dim3(16, 64, 1), 256, 0, stream>>>(t1, 384, wib + 2048 * 384, 384, NTOK, 2048, 384, nullptr, t2h, nullptr);
    k_gemm<4><<<dim3(3, 64, 2),  256, 0, stream>>>(t2h, 2048, woa2 + 2048,   4096, NTOK, 384, 1024, t3f, nullptr, nullptr);
    k_cvt<<<3072, 256, 0, stream>>>(t3f, t3);
    k_gemm<3><<<dim3(8, 64, 1), 256, 0, stream>>>(t3, 384, wob2, 384, NTOK, 1024, 384, out, nullptr, x2);
}

// Round 7
// 553.521 us; speedup vs baseline: 1.1486x; 1.1486x over previous
//
#include <hip/hip_runtime.h>
#include <hip/hip_bf16.h>
#include <stdint.h>

// ---------- problem constants ----------
#define NTOK 8192   // B*T

typedef unsigned short u16;
typedef __attribute__((ext_vector_type(4))) float f32x4;
typedef __attribute__((ext_vector_type(8))) short s16x8;
typedef __attribute__((ext_vector_type(8))) u16   u16x8;
typedef __attribute__((ext_vector_type(4))) u16   u16x4;

__device__ __forceinline__ float fast_exp2(float x) {
    return __builtin_amdgcn_exp2f(x);
}
__device__ __forceinline__ u16 f2bf(float f) {
    uint32_t u = __float_as_uint(f);
    u = (u + 0x7FFFu + ((u >> 16) & 1u)) >> 16;   // RNE
    return (u16)u;
}
__device__ __forceinline__ u16 f2bf_fast(float f) {
    return (u16)((__float_as_uint(f) + 0x8000u) >> 16);
}
__device__ __forceinline__ float bf2f(u16 h) {
    return __uint_as_float(((uint32_t)h) << 16);
}
__device__ __forceinline__ void async_cp16(const void* g, void* l) {
    __builtin_amdgcn_global_load_lds(
        (const __attribute__((address_space(1))) void*)g,
        (__attribute__((address_space(3))) void*)l, 16, 0, 0);
}
__device__ __forceinline__ void wait_vm4()   { asm volatile("s_waitcnt vmcnt(4)" ::: "memory"); }
__device__ __forceinline__ void wait_vm0()   { asm volatile("s_waitcnt vmcnt(0)" ::: "memory"); }
__device__ __forceinline__ void wait_lgkm0() { asm volatile("s_waitcnt lgkmcnt(0)" ::: "memory"); }
__device__ __forceinline__ void raw_barrier(){ asm volatile("s_barrier" ::: "memory"); }

// ---------- all weight transposes in one launch: f32 [K][N] -> bf16 [N][K] ----------
struct TDesc { const float* s; u16* d; int K; int N; int tile0; };
struct TPack { TDesc t[8]; };

__global__ __launch_bounds__(256) void k_transpose_all(TPack p)
{
    __shared__ float tile[32][33];
    int bid = blockIdx.x;
    int i = 0;
    #pragma unroll
    for (int j = 1; j < 8; j++) if (bid >= p.t[j].tile0) i = j;
    const float* src = p.t[i].s;
    u16* dst = p.t[i].d;
    int K = p.t[i].K, N = p.t[i].N;
    int local = bid - p.t[i].tile0;
    int nx = N >> 5;
    int n0 = (local % nx) * 32, k0 = (local / nx) * 32;
    int tx = threadIdx.x, ty = threadIdx.y;      // block (32,8)
    #pragma unroll
    for (int r = 0; r < 32; r += 8)
        tile[ty + r][tx] = src[(size_t)(k0 + ty + r) * N + n0 + tx];
    __syncthreads();
    #pragma unroll
    for (int r = 0; r < 32; r += 8)
        dst[(size_t)(n0 + ty + r) * K + k0 + tx] = f2bf(tile[tx][ty + r]);
}

// ---------- f32 -> bf16 flat convert ----------
__global__ __launch_bounds__(256) void k_cvt(
    const float* __restrict__ in, u16* __restrict__ out)
{
    int i = (blockIdx.x * 256 + threadIdx.x) * 4;
    f32x4 v = *(const f32x4*)&in[i];
    u16x4 o;
    #pragma unroll
    for (int j = 0; j < 4; j++) o[j] = f2bf(v[j]);
    *(u16x4*)&out[i] = o;
}

// ---------- RMSNorm: f32 in, bf16 out ----------
template<int W>
__global__ __launch_bounds__(256) void k_rmsnorm(
    const float* __restrict__ x, const float* __restrict__ w, u16* __restrict__ out)
{
    constexpr int E = W / 256;
    int row = blockIdx.x, tid = threadIdx.x;
    const float* xr = x + (size_t)row * W;
    float v[E]; float ss = 0.f;
    #pragma unroll
    for (int i = 0; i < E; i++) { v[i] = xr[tid + i * 256]; ss += v[i] * v[i]; }
    #pragma unroll
    for (int m = 1; m < 64; m <<= 1) ss += __shfl_xor(ss, m, 64);
    __shared__ float red[4];
    if ((tid & 63) == 0) red[tid >> 6] = ss;
    __syncthreads();
    ss = red[0] + red[1] + red[2] + red[3];
    float scale = rsqrtf(ss / (float)W + 1e-6f);
    u16* orow = out + (size_t)row * W;
    #pragma unroll
    for (int i = 0; i < E; i++)
        orow[tid + i * 256] = f2bf(w[tid + i * 256] * (v[i] * scale));
}

// ---------- GEMM 128x128 tile, double-buffered pipelined K-loop ----------
// EPI: 0 = f32 store; 1 = bf16 store; 2 = gelu(tanh)+bf16; 3 = f32 + resid
template<int EPI>
__global__ __launch_bounds__(256) void k_gemm(
    const u16* __restrict__ A, int lda,
    const u16* __restrict__ Bt, int ldb,
    int M, int N, int K,
    float* __restrict__ outF, u16* __restrict__ outB,
    const float* __restrict__ resid)
{
    __shared__ __align__(16) u16 As[2][4096];
    __shared__ __align__(16) u16 Bs[2][4096];
    int tid = threadIdx.x;
    int w = tid >> 6, lane = tid & 63;
    int m0 = blockIdx.y * 128, n0 = blockIdx.x * 128;
    int wm = w & 1, wn = w >> 1;
    int lr = lane & 15, lq = lane >> 4;

    f32x4 acc[4][4];
    #pragma unroll
    for (int i = 0; i < 4; i++)
        #pragma unroll
        for (int j = 0; j < 4; j++) acc[i][j] = (f32x4)(0.f);

    int ar = tid >> 2;
    int ac = (tid & 3) * 8;
    const u16* Ag = A  + (size_t)(m0 + ar) * lda + ac;
    const u16* Bg = Bt + (size_t)(n0 + ar) * ldb + ac;
    int lo = w * 512;

    auto stage = [&](int kt, int s) {
        const u16* a  = Ag + kt * 32;
        const u16* bp = Bg + kt * 32;
        async_cp16(a,                     &As[s][lo]);
        async_cp16(a + (size_t)64 * lda,  &As[s][lo + 2048]);
        async_cp16(bp,                    &Bs[s][lo]);
        async_cp16(bp + (size_t)64 * ldb, &Bs[s][lo + 2048]);
    };

    int nk = K >> 5;
    stage(0, 0);
    stage(1, 1);
    for (int k = 0; k < nk; k++) {
        if (k + 1 < nk) wait_vm4(); else wait_vm0();
        raw_barrier();
        int s = k & 1;
        s16x8 af[4], bfr[4];
        #pragma unroll
        for (int ms = 0; ms < 4; ms++)
            af[ms] = *reinterpret_cast<const s16x8*>(&As[s][(wm * 64 + ms * 16 + lr) * 32 + lq * 8]);
        #pragma unroll
        for (int ns = 0; ns < 4; ns++)
            bfr[ns] = *reinterpret_cast<const s16x8*>(&Bs[s][(wn * 64 + ns * 16 + lr) * 32 + lq * 8]);
        #pragma unroll
        for (int ms = 0; ms < 4; ms++)
            #pragma unroll
            for (int ns = 0; ns < 4; ns++)
                acc[ms][ns] = __builtin_amdgcn_mfma_f32_16x16x32_bf16(af[ms], bfr[ns], acc[ms][ns], 0, 0, 0);
        wait_lgkm0();
        raw_barrier();
        if (k + 2 < nk) stage(k + 2, s);
    }

    #pragma unroll
    for (int ms = 0; ms < 4; ms++) {
        #pragma unroll
        for (int ns = 0; ns < 4; ns++) {
            int col = n0 + wn * 64 + ns * 16 + lr;
            #pragma unroll
            for (int r = 0; r < 4; r++) {
                int row = m0 + wm * 64 + ms * 16 + lq * 4 + r;
                float v = acc[ms][ns][r];
                size_t idx = (size_t)row * N + col;
                if (EPI == 0) {
                    outF[idx] = v;
                } else if (EPI == 1) {
                    outB[idx] = f2bf(v);
                } else if (EPI == 2) {
                    float t = 0.7978845608028654f * (v + 0.044715f * v * v * v);
                    outB[idx] = f2bf(0.5f * v * (1.f + tanhf(t)));
                } else {
                    outF[idx] = v + resid[idx];
                }
            }
        }
    }
}

// ---------- GEMM 64x64 tile (for skinny-N, grid-starved shapes) ----------
// BK=64, double-buffered vmcnt(4) pipeline, 32 KB LDS -> 5 blocks/CU.
// EPI: 0 = f32 store; 1 = bf16 store
template<int EPI>
__global__ __launch_bounds__(256) void k_gemm64(
    const u16* __restrict__ A, int lda,
    const u16* __restrict__ Bt, int ldb,
    int M, int N, int K,
    float* __restrict__ outF, u16* __restrict__ outB)
{
    __shared__ __align__(16) u16 As[2][4096];   // [kc2][64 rows][32 u16]
    __shared__ __align__(16) u16 Bs[2][4096];
    int tid = threadIdx.x;
    int w = tid >> 6, lane = tid & 63;
    int m0 = blockIdx.y * 64, n0 = blockIdx.x * 64;
    int wm = w & 1, wn = w >> 1;
    int lr = lane & 15, lq = lane >> 4;

    f32x4 acc[2][2];
    #pragma unroll
    for (int i = 0; i < 2; i++)
        #pragma unroll
        for (int j = 0; j < 2; j++) acc[i][j] = (f32x4)(0.f);

    int srow = tid >> 2;            // 0..63
    int sq   = tid & 3;             // 16B quarter within 32-u16 chunk
    const u16* Ag = A  + (size_t)(m0 + srow) * lda + sq * 8;
    const u16* Bg = Bt + (size_t)(n0 + srow) * ldb + sq * 8;
    int lo = srow * 32 + sq * 8;

    auto stage = [&](int kt, int s) {
        const u16* a  = Ag + kt * 64;
        const u16* bp = Bg + kt * 64;
        async_cp16(a,       &As[s][lo]);
        async_cp16(a + 32,  &As[s][2048 + lo]);
        async_cp16(bp,      &Bs[s][lo]);
        async_cp16(bp + 32, &Bs[s][2048 + lo]);
    };

    int nk = K >> 6;
    stage(0, 0);
    stage(1, 1);
    for (int k = 0; k < nk; k++) {
        if (k + 1 < nk) wait_vm4(); else wait_vm0();
        raw_barrier();
        int s = k & 1;
        s16x8 af[2][2], bfr[2][2];
        #pragma unroll
        for (int kc = 0; kc < 2; kc++) {
            #pragma unroll
            for (int ms = 0; ms < 2; ms++)
                af[ms][kc] = *reinterpret_cast<const s16x8*>(
                    &As[s][kc * 2048 + (wm * 32 + ms * 16 + lr) * 32 + lq * 8]);
            #pragma unroll
            for (int ns = 0; ns < 2; ns++)
                bfr[ns][kc] = *reinterpret_cast<const s16x8*>(
                    &Bs[s][kc * 2048 + (wn * 32 + ns * 16 + lr) * 32 + lq * 8]);
        }
        #pragma unroll
        for (int kc = 0; kc < 2; kc++)
            #pragma unroll
            for (int ms = 0; ms < 2; ms++)
                #pragma unroll
                for (int ns = 0; ns < 2; ns++)
                    acc[ms][ns] = __builtin_amdgcn_mfma_f32_16x16x32_bf16(
                        af[ms][kc], bfr[ns][kc], acc[ms][ns], 0, 0, 0);
        wait_lgkm0();
        raw_barrier();
        if (k + 2 < nk) stage(k + 2, s);
    }

    #pragma unroll
    for (int ms = 0; ms < 2; ms++) {
        #pragma unroll
        for (int ns = 0; ns < 2; ns++) {
            int col = n0 + wn * 32 + ns * 16 + lr;
            #pragma unroll
            for (int r = 0; r < 4; r++) {
                int row = m0 + wm * 32 + ms * 16 + lq * 4 + r;
                float v = acc[ms][ns][r];
                size_t idx = (size_t)row * N + col;
                if (EPI == 0) outF[idx] = v;
                else          outB[idx] = f2bf(v);
            }
        }
    }
}

// ---------- RoPE (x8 vectorized) ----------
__global__ __launch_bounds__(256) void k_rope(
    const u16* __restrict__ q, const u16* __restrict__ kv,
    const float* __restrict__ cosb, const float* __restrict__ sinb,
    u16* __restrict__ q_r, u16* __restrict__ k_r)
{
    const float QS = 0.125f * 1.4426950408889634f;
    int idx = blockIdx.x * 256 + threadIdx.x;    // B*T*H*8 threads
    int g = idx & 7;
    int h = (idx >> 3) & 15;
    int t = (idx >> 7) & 2047;
    int b = idx >> 18;
    size_t qsrc = ((size_t)((b * 2048 + t) * 16 + h)) * 64 + g * 8;
    size_t ksrc = ((size_t)((b * 2048 + t) * 16 + h)) * 128 + g * 8;
    u16x8 qa = *(const u16x8*)&q[qsrc];
    u16x8 ka = *(const u16x8*)&kv[ksrc];
    u16x8 qo, ko;
    if (g < 4) {
        int pd = ((g ^ 2) - g) * 8;
        u16x8 qp = *(const u16x8*)&q[qsrc + pd];
        u16x8 kp = *(const u16x8*)&kv[ksrc + pd];
        float sgn = (g < 2) ? -1.f : 1.f;
        const float* cp = &cosb[t * 32 + g * 8];
        const float* sp = &sinb[t * 32 + g * 8];
        #pragma unroll
        for (int j = 0; j < 8; j++) {
            float c = cp[j], s = sp[j];
            qo[j] = f2bf((bf2f(qa[j]) * c + sgn * bf2f(qp[j]) * s) * QS);
            ko[j] = f2bf(bf2f(ka[j]) * c + sgn * bf2f(kp[j]) * s);
        }
    } else {
        #pragma unroll
        for (int j = 0; j < 8; j++) {
            qo[j] = f2bf(bf2f(qa[j]) * QS);
            ko[j] = ka[j];
        }
    }
    size_t dst = ((size_t)(b * 16 + h) * 2048 + t) * 64 + g * 8;
    *(u16x8*)&q_r[dst] = qo;
    *(u16x8*)&k_r[dst] = ko;
}

// ---------- V transpose: kv [B,T,H,128] (v half) -> v_t [B,H,64,T] ----------
__global__ __launch_bounds__(256) void k_vtrans(
    const u16* __restrict__ kv, u16* __restrict__ v_t)
{
    __shared__ u16 tile[64][72];
    int bh = blockIdx.y;
    int b = bh >> 4, h = bh & 15;
    int t0 = blockIdx.x * 64;
    int tid = threadIdx.x;
    int r = tid >> 2;
    int c4 = (tid & 3) * 16;
    const u16* src = kv + ((size_t)((b * 2048 + t0 + r) * 16 + h)) * 128 + 64;
    #pragma unroll
    for (int j = 0; j < 16; j += 8)
        *(u16x8*)&tile[r][c4 + j] = *(const u16x8*)&src[c4 + j];
    __syncthreads();
    int dd = tid >> 2;
    u16* dst = v_t + ((size_t)bh * 64 + dd) * 2048 + t0;
    #pragma unroll
    for (int j0 = 0; j0 < 16; j0 += 8) {
        u16x8 vv;
        #pragma unroll
        for (int j = 0; j < 8; j++) vv[j] = tile[c4 + j0 + j][dd];
        *(u16x8*)&dst[c4 + j0] = vv;
    }
}

// ---------- flash attention v5: double-buffered K/V staging ----------
__global__ __launch_bounds__(256) void k_attn(
    const u16* __restrict__ q_r, const u16* __restrict__ k_r,
    const u16* __restrict__ v_t, u16* __restrict__ ctx)
{
    __shared__ __align__(16) u16 Ks[2][4096];
    __shared__ __align__(16) u16 Vs[2][4096];
    __shared__ __align__(16) u16 Ps[4][2048];
    int tid = threadIdx.x, w = tid >> 6, lane = tid & 63;
    int bh = blockIdx.y;
    int b = bh >> 4, h = bh & 15;
    int q0 = blockIdx.x * 128 + w * 32;
    const u16* Qp = q_r + (size_t)bh * 2048 * 64;
    const u16* Kp = k_r + (size_t)bh * 2048 * 64;
    const u16* Vp = v_t + (size_t)bh * 64 * 2048;
    int lr = lane & 15, lq = lane >> 4;
    int rot = (lr * 8) & 63;

    s16x8 qf[2][2];
    #pragma unroll
    for (int qc = 0; qc < 2; qc++)
        #pragma unroll
        for (int kf = 0; kf < 2; kf++)
            qf[qc][kf] = *(const s16x8*)&Qp[(size_t)(q0 + qc * 16 + lr) * 64 + kf * 32 + lq * 8];

    const u16* gstage;
    u16 *lp0, *lp1;
    size_t grow;
    if (w < 2) {
        gstage = Kp + (size_t)(lane >> 2) * 64 + w * 32 + (lane & 3) * 8;
        lp0 = &Ks[0][w * 2048]; lp1 = &Ks[1][w * 2048];
        grow = 16 * 64;
    } else {
        gstage = Vp + (size_t)(lane >> 2) * 2048 + (w - 2) * 32 + (lane & 3) * 8;
        lp0 = &Vs[0][(w - 2) * 2048]; lp1 = &Vs[1][(w - 2) * 2048];
        grow = 16 * 2048;
    }
    auto stage = [&](int kt, int s) {
        size_t goff = (w < 2) ? (size_t)kt * 64 : (size_t)kt;
        u16* lp = s ? lp1 : lp0;
        #pragma unroll
        for (int g = 0; g < 4; g++)
            async_cp16(gstage + goff + g * grow, lp + g * 512);
    };

    float l0 = 0.f, l1 = 0.f;
    f32x4 o[2][4];
    #pragma unroll
    for (int qt = 0; qt < 2; qt++)
        #pragma unroll
        for (int ds = 0; ds < 4; ds++) o[qt][ds] = (f32x4)(0.f);

    u16* Pw = Ps[w];

    stage(0, 0);
    stage(64, 1);
    for (int k = 0; k < 32; k++) {
        if (k < 31) wait_vm4(); else wait_vm0();
        raw_barrier();
        int s = k & 1;
        const u16* Ksb = Ks[s];
        const u16* Vsb = Vs[s];

        f32x4 sc[2][4];
        #pragma unroll
        for (int ns = 0; ns < 4; ns++) {
            s16x8 a0 = *(const s16x8*)&Ksb[(ns * 16 + lr) * 32 + lq * 8];
            s16x8 a1 = *(const s16x8*)&Ksb[2048 + (ns * 16 + lr) * 32 + lq * 8];
            #pragma unroll
            for (int qc = 0; qc < 2; qc++) {
                f32x4 t = (f32x4)(0.f);
                t = __builtin_amdgcn_mfma_f32_16x16x32_bf16(a0, qf[qc][0], t, 0, 0, 0);
                t = __builtin_amdgcn_mfma_f32_16x16x32_bf16(a1, qf[qc][1], t, 0, 0, 0);
                sc[qc][ns] = t;
            }
        }

        float rs0 = 0.f, rs1 = 0.f;
        #pragma unroll
        for (int ns = 0; ns < 4; ns++) {
            u16x4 pk0, pk1;
            #pragma unroll
            for (int r = 0; r < 4; r++) {
                float p0 = fast_exp2(sc[0][ns][r]);
                float p1 = fast_exp2(sc[1][ns][r]);
                rs0 += p0; rs1 += p1;
                pk0[r] = f2bf_fast(p0);
                pk1[r] = f2bf_fast(p1);
            }
            int c0 = (ns * 16 + lq * 4 + rot) & 63;
            *(u16x4*)&Pw[lr * 64 + c0] = pk0;
            *(u16x4*)&Pw[(16 + lr) * 64 + c0] = pk1;
        }
        rs0 += __shfl_xor(rs0, 16, 64);
        rs0 += __shfl_xor(rs0, 32, 64);
        rs1 += __shfl_xor(rs1, 16, 64);
        rs1 += __shfl_xor(rs1, 32, 64);
        l0 += rs0;
        l1 += rs1;

        #pragma unroll
        for (int kf = 0; kf < 2; kf++) {
            int cr = (kf * 32 + lq * 8 + rot) & 63;
            s16x8 pf0 = *(const s16x8*)&Pw[lr * 64 + cr];
            s16x8 pf1 = *(const s16x8*)&Pw[(16 + lr) * 64 + cr];
            #pragma unroll
            for (int ds = 0; ds < 4; ds++) {
                s16x8 vf = *(const s16x8*)&Vsb[kf * 2048 + (ds * 16 + lr) * 32 + lq * 8];
                o[0][ds] = __builtin_amdgcn_mfma_f32_16x16x32_bf16(pf0, vf, o[0][ds], 0, 0, 0);
                o[1][ds] = __builtin_amdgcn_mfma_f32_16x16x32_bf16(pf1, vf, o[1][ds], 0, 0, 0);
            }
        }
        wait_lgkm0();
        raw_barrier();
        if (k + 2 < 32) stage((k + 2) * 64, s);
    }

    #pragma unroll
    for (int qt = 0; qt < 2; qt++) {
        float lv = qt ? l1 : l0;
        float li[4];
        #pragma unroll
        for (int r = 0; r < 4; r++) li[r] = 1.f / __shfl(lv, lq * 4 + r, 64);
        #pragma unroll
        for (int ds = 0; ds < 4; ds++)
            #pragma unroll
            for (int r = 0; r < 4; r++) {
                int tq = q0 + qt * 16 + lq * 4 + r;
                float v = o[qt][ds][r] * li[r];
                ctx[((size_t)(b * 2048) + tq) * 1024 + h * 64 + ds * 16 + lr] = f2bf(v);
            }
    }
}

// ---------- host ----------
extern "C" void kernel_launch(void* const* d_in, const int* in_sizes, int n_in,
                              void* d_out, int out_size, void* d_ws, size_t ws_size,
                              hipStream_t stream) {
    (void)in_sizes; (void)n_in; (void)out_size; (void)ws_size;
    const float* x     = (const float*)d_in[0];
    const float* ln1   = (const float*)d_in[1];
    const float* alnw  = (const float*)d_in[2];
    const float* qkv_a = (const float*)d_in[3];
    const float* q_b   = (const float*)d_in[4];
    const float* kv_b  = (const float*)d_in[5];
    const float* o_a   = (const float*)d_in[6];
    const float* o_b   = (const float*)d_in[7];
    const float* ln2   = (const float*)d_in[8];
    const float* in_a  = (const float*)d_in[9];
    const float* in_b  = (const float*)d_in[10];
    const float* out_a = (const float*)d_in[11];
    const float* out_b = (const float*)d_in[12];
    const float* cosb  = (const float*)d_in[13];
    const float* sinb  = (const float*)d_in[14];
    float* out = (float*)d_out;
    char* ws = (char*)d_ws;

    // ---- weights bf16 [0, 15728640) ----
    u16* wqkv = (u16*)ws;              // 768x1024
    u16* wq   = wqkv + 786432;         // 1024x512
    u16* wkv  = wq   + 524288;         // 2048x256
    u16* wob  = wkv  + 524288;         // 1024x512 (o_b^T)
    u16* wia  = wob  + 524288;         // 384x1024
    u16* wib  = wia  + 393216;         // 4096x384
    u16* woa2 = wib  + 1572864;        // 384x4096 (out_a^T)
    u16* wob2 = woa2 + 1572864;        // 1024x384
    u16* woan = wob2 + 393216;         // 1024x512 (o_a cast)
    u16* woab = woan + 524288;         // 1024x1024 fused (o_a@o_b)^T

    // ---- activations, base G = ws + 15728640 ----
    char* G = ws + 15728640;
    u16*  hbuf  = (u16*)(G + 0);              // 16.8 MB [rms1 -> qkv]
    float* lat_raw = (float*)(G + 16777216);  // 25.2 MB [qkv -> rms768]
    u16*  lat   = (u16*)(G + 41943040);       // 12.6 MB [rms768 -> q,kv]
    u16*  qbuf  = (u16*)(G + 54525952);       // 16.8 MB [q -> rope]
    u16*  kvbuf = (u16*)(G + 71303168);       // 33.6 MB [kv -> rope,vtrans]
    u16*  q_r   = (u16*)(G + 0);              // reuse hbuf      [rope -> attn]
    u16*  k_r   = (u16*)(G + 16777216);       // reuse lat_raw   [rope -> attn]
    u16*  v_t   = (u16*)(G + 33554432);       // lat_raw tail+lat [vtrans -> attn]
    u16*  ctx   = (u16*)(G + 54525952);       // reuse qbuf      [attn -> o-gemm]
    float* x2   = (float*)(G + 0);            // 33.6 MB, reuse q_r/k_r [o -> final]
    u16*  h2    = (u16*)(G + 33554432);       // reuse v_t       [rms2 -> in_a]
    u16*  t1    = (u16*)(G + 50331648);       // 6.3 MB          [in_a -> in_b]
    u16*  t2    = (u16*)(G + 56623104);       // 64 MB           [in_b -> out_a]
    u16*  t3    = (u16*)(G + 50331648);       // reuse t1        [out_a -> out_b]

    TPack tp;
    tp.t[0] = { qkv_a, wqkv, 1024, 768,  0 };
    tp.t[1] = { q_b,   wq,   512,  1024, 768 };
    tp.t[2] = { kv_b,  wkv,  256,  2048, 1280 };
    tp.t[3] = { o_b,   wob,  512,  1024, 1792 };
    tp.t[4] = { in_a,  wia,  1024, 384,  2304 };
    tp.t[5] = { in_b,  wib,  384,  4096, 2688 };
    tp.t[6] = { out_a, woa2, 4096, 384,  4224 };
    tp.t[7] = { out_b, wob2, 384,  1024, 5760 };
    k_transpose_all<<<6144, dim3(32, 8), 0, stream>>>(tp);
    k_cvt<<<512, 256, 0, stream>>>(o_a, woan);
    // fused o-weight: W^T = o_b^T @ o_a  (bf16), [1024][1024]
    k_gemm64<1><<<dim3(16, 16), 256, 0, stream>>>(wob, 512, woan, 512, 1024, 1024, 512, nullptr, woab);

    k_rmsnorm<1024><<<NTOK, 256, 0, stream>>>(x, ln1, hbuf);
    k_gemm64<0><<<dim3(12, 128), 256, 0, stream>>>(hbuf, 1024, wqkv, 1024, NTOK, 768, 1024, lat_raw, nullptr);
    k_rmsnorm<768><<<NTOK, 256, 0, stream>>>(lat_raw, alnw, lat);
    k_gemm<1><<<dim3(8, 64),  256, 0, stream>>>(lat,       768, wq,  512, NTOK, 1024, 512, nullptr, qbuf,  nullptr);
    k_gemm<1><<<dim3(16, 64), 256, 0, stream>>>(lat + 512, 768, wkv, 256, NTOK, 2048, 256, nullptr, kvbuf, nullptr);
    k_rope<<<4096, 256, 0, stream>>>(qbuf, kvbuf, cosb, sinb, q_r, k_r);
    k_vtrans<<<dim3(32, 64), 256, 0, stream>>>(kvbuf, v_t);
    k_attn<<<dim3(16, 64), 256, 0, stream>>>(q_r, k_r, v_t, ctx);
    // attn_out + residual in one GEMM via fused weight
    k_gemm<3><<<dim3(8, 64), 256, 0, stream>>>(ctx, 1024, woab, 1024, NTOK, 1024, 1024, x2, nullptr, x);
    k_rmsnorm<1024><<<NTOK, 256, 0, stream>>>(x2, ln2, h2);
    k_gemm64<1><<<dim3(6, 128), 256, 0, stream>>>(h2, 1024, wia, 1024, NTOK, 384, 1024, nullptr, t1);
    k_gemm<2><<<dim3(32, 64), 256, 0, stream>>>(t1, 384, wib, 384, NTOK, 4096, 384, nullptr, t2, nullptr);
    k_gemm64<1><<<dim3(6, 128), 256, 0, stream>>>(t2, 4096, woa2, 4096, NTOK, 384, 4096, nullptr, t3);
    k_gemm<3><<<dim3(8, 64), 256, 0, stream>>>(t3, 384, wob2, 384, NTOK, 1024, 384, out, nullptr, x2);
}